// Round 7
// baseline (241.992 us; speedup 1.0000x reference)
//
#include <hip/hip_runtime.h>

typedef short s16x8 __attribute__((ext_vector_type(8)));
typedef float f32x4 __attribute__((ext_vector_type(4)));
typedef float f32x16 __attribute__((ext_vector_type(16)));
typedef unsigned int u32x4 __attribute__((ext_vector_type(4)));

__device__ __forceinline__ unsigned short f2bf(float f) {
    unsigned int u = __float_as_uint(f);
    u += 0x7fff + ((u >> 16) & 1);   // RNE
    return (unsigned short)(u >> 16);
}
__device__ __forceinline__ float bf2f(unsigned short h) {
    return __uint_as_float(((unsigned int)h) << 16);
}
__device__ __forceinline__ unsigned pack2bf(float lo, float hi) {
    return (unsigned)f2bf(lo) | ((unsigned)f2bf(hi) << 16);   // RNE both halves
}
__device__ __forceinline__ f32x4 mfma16(s16x8 a, s16x8 b, f32x4 c) {
    return __builtin_amdgcn_mfma_f32_16x16x32_bf16(a, b, c, 0, 0, 0);
}
__device__ __forceinline__ f32x16 mfma32(s16x8 a, s16x8 b, f32x16 c) {
    return __builtin_amdgcn_mfma_f32_32x32x16_bf16(a, b, c, 0, 0, 0);
}
__device__ __forceinline__ void async16(const void* g, void* l) {
    __builtin_amdgcn_global_load_lds(
        (const __attribute__((address_space(1))) void*)g,
        (__attribute__((address_space(3))) void*)l, 16, 0, 0);
}

#define ROPE_C (-13.287712379549449f / 32.0f)

// ---------------------------------------------------------------------------
// fp32 -> bf16: x -> xb, wq|wk|wv -> wqkvb, wp -> wpb.
// ---------------------------------------------------------------------------
__global__ __launch_bounds__(256) void convert_all(
    const float* __restrict__ x,  const float* __restrict__ wq,
    const float* __restrict__ wk, const float* __restrict__ wv,
    const float* __restrict__ wp,
    unsigned short* __restrict__ xb, unsigned short* __restrict__ wqkvb,
    unsigned short* __restrict__ wpb)
{
    const size_t XN = 2048u * 1024u, WN = 1024u * 1024u;
    size_t e = ((size_t)blockIdx.x * 256 + threadIdx.x) * 4;
    const float* s; unsigned short* d;
    if (e < XN)                { s = x  + e;               d = xb    + e; }
    else if (e < XN + WN)      { s = wq + (e - XN);        d = wqkvb + (e - XN); }
    else if (e < XN + 2 * WN)  { s = wk + (e - XN - WN);   d = wqkvb + (e - XN); }
    else if (e < XN + 3 * WN)  { s = wv + (e - XN - 2*WN); d = wqkvb + (e - XN); }
    else                       { s = wp + (e - XN - 3*WN); d = wpb   + (e - XN - 3*WN); }
    float4 v = *(const float4*)s;
    ushort4 o;
    o.x = f2bf(v.x); o.y = f2bf(v.y); o.z = f2bf(v.z); o.w = f2bf(v.w);
    *(ushort4*)d = o;
}

// ---------------------------------------------------------------------------
// bf16 GEMM (m97 structure, BK=64): C = A[M x 1024] * B[N x 1024]^T.
// BM x BN tile, 4 waves (2x2), wave tile (BM/2)x(BN/2), global_load_lds.
// ROPE=1 (requires BN=128): n-blocks < 16 are q/k sections of the fused qkv
// output; wave tile = 64 cols = one head.
//
// *** RoPE binding order IS CORRECT AS WRITTEN — do not "fix" it. ***
// __sincosf(ang,&c,&s) binds c=sin(ang), s=cos(ang); the update
//   q'[i] = e0*c + e1*s ; q'[i+32] = e1*c - e0*s
// is then R(theta - pi/2): the reference rotation composed with a CONSTANT
// 90-degree rotation. Applied identically to q and k, the relative rotation
// R(th_n - th_m) — the only thing logits see — matches the reference
// exactly. Binding sin-first (R4) gives R(-theta) -> INVERSE relative
// rotation -> absmax 2.9e-2 fail.
//
// Q-prescale (R6): q section (n0<1024) additionally scaled by 0.125 = 2^-3
// (exact in bf16 -> exp argument in attn is BIT-IDENTICAL to scaling at
// QK time); removes the *0.125f VALU mul from the attn hot loop.
//
// NOTE (R3): at M=2048,N=3072 the 128x128 tile gives only 384 blocks
// (occupancy 7.3%, MfmaUtil 7.9%, 57us) — 64x128 (768 blocks) is right for
// this shape. __sincosf fast path: angle err <= 2048*2^-24 ~ 1.2e-4 rad,
// output perturbation ~1e-4 << 9.7e-4 threshold.
// ---------------------------------------------------------------------------
template<int BM, int BN, int C32, int ROPE>
__global__ __launch_bounds__(256) void gemm_mfma(
    const unsigned short* __restrict__ A,
    const unsigned short* __restrict__ B,
    void* __restrict__ C, int Ntot)
{
    constexpr int MT = BM / 32, NT = BN / 32;
    __shared__ unsigned short As[BM * 64];
    __shared__ unsigned short Bs[BN * 64];

    const int tid  = threadIdx.x;
    const int wave = tid >> 6, lane = tid & 63;
    const int l16  = lane & 15, quad = lane >> 4;
    const int m0   = blockIdx.y * BM, n0 = blockIdx.x * BN;
    const int wm   = (wave & 1) * (BM / 2), wn = (wave >> 1) * (BN / 2);

    const int srow8 = lane >> 3;        // 0..7
    const int scol  = (lane & 7) * 8;   // 0..56

    f32x4 acc[MT][NT] = {};

    for (int k0 = 0; k0 < 1024; k0 += 64) {
        #pragma unroll
        for (int i = 0; i < BM / 32; i++) {
            int j = wave * (BM / 32) + i;
            async16(A + (size_t)(m0 + j * 8 + srow8) * 1024 + k0 + scol, &As[j * 512]);
        }
        #pragma unroll
        for (int i = 0; i < BN / 32; i++) {
            int j = wave * (BN / 32) + i;
            async16(B + (size_t)(n0 + j * 8 + srow8) * 1024 + k0 + scol, &Bs[j * 512]);
        }
        __syncthreads();

        #pragma unroll
        for (int ks = 0; ks < 2; ks++) {
            s16x8 af[MT], bfr[NT];
            #pragma unroll
            for (int mt = 0; mt < MT; mt++)
                af[mt] = *(const s16x8*)&As[(wm + mt * 16 + l16) * 64 + ks * 32 + quad * 8];
            #pragma unroll
            for (int nt = 0; nt < NT; nt++)
                bfr[nt] = *(const s16x8*)&Bs[(wn + nt * 16 + l16) * 64 + ks * 32 + quad * 8];
            #pragma unroll
            for (int mt = 0; mt < MT; mt++)
                #pragma unroll
                for (int nt = 0; nt < NT; nt++)
                    acc[mt][nt] = mfma16(af[mt], bfr[nt], acc[mt][nt]);
        }
        __syncthreads();
    }

    // Fused RoPE on q/k sections (in-register, fp32, before bf16 store)
    if constexpr (ROPE) {
        if (n0 < 2048) {
            const float sc = (n0 < 1024) ? 0.125f : 1.0f;   // Q-prescale
            #pragma unroll
            for (int mt = 0; mt < MT; mt++)
                #pragma unroll
                for (int r = 0; r < 4; r++) {
                    int m = m0 + wm + mt * 16 + quad * 4 + r;   // token
                    #pragma unroll
                    for (int nt = 0; nt < 2; nt++) {
                        int i = nt * 16 + l16;                  // 0..31 in head
                        float ang = (float)m * exp2f((float)i * ROPE_C);
                        float c, s;
                        __sincosf(ang, &c, &s);   // c=sin, s=cos — see header note
                        c *= sc; s *= sc;
                        float e0 = acc[mt][nt][r], e1 = acc[mt][nt + 2][r];
                        acc[mt][nt][r]     = e0 * c + e1 * s;
                        acc[mt][nt + 2][r] = e1 * c - e0 * s;
                    }
                }
        }
    }

    // C/D layout: col = lane&15, row = quad*4 + reg
    #pragma unroll
    for (int mt = 0; mt < MT; mt++)
        #pragma unroll
        for (int nt = 0; nt < NT; nt++)
            #pragma unroll
            for (int r = 0; r < 4; r++) {
                int m = m0 + wm + mt * 16 + quad * 4 + r;
                int n = n0 + wn + nt * 16 + l16;
                size_t idx = (size_t)m * Ntot + n;
                if (C32) ((float*)C)[idx] = acc[mt][nt][r];
                else     ((unsigned short*)C)[idx] = f2bf(acc[mt][nt][r]);
            }
}

// ---------------------------------------------------------------------------
// Split-K flash attention, 32x32x16 MFMA, operand-swapped QK (verified r12).
// grid (16 qblk(128q), 16 heads, 4 ksplit(512k)). bf16 numerator partials.
// P never touches LDS: QK C/D reg r=4c'+j of lane (l32,h) holds
// key(in group g) = 8c' + 4h + j, q = l32. PV A-frag for fragment c=2g+f,
// word t must hold keys(within c*16) 8h + {2t,2t+1}.
//   own e[0..3] = k 4h+{0..3} (regs 8f..), own e[4..7] = k 8+4h+{0..3}.
// pack RNE-bf16 pairs: lo0={e0,e1} lo1={e2,e3} hi0={e4,e5} hi1={e6,e7}.
// v_permlane32_swap_b32 dst,src swaps dst[32:63] <-> src[0:31]:
//   swap(lo,hi): lo' = {own lo | partner hi} = word0/1 for h=0/h=1;
//                hi' = {partner lo | own hi} = word2/3.
// NOTE: conversion stays f2bf (RNE). v_cvt_pk_bf16_f32 truncates ->
// numerator biased -2^-9 vs f32 lsum denominator -> absmax 8e-3 (R2 fail).
//
// R6: double-buffered K/V staging (T14 issue-early/commit-late).
// Per iter: issue global->reg loads for t+1, compute t from buf[p],
// reg->LDS commit into buf[p^1], ONE barrier. Race audit: compute(t) reads
// buf[p] while commit(t) writes buf[p^1] (disjoint); the end barrier
// separates iter-t reads of buf[p] from iter-t+1 writes of buf[p].
// Q is pre-scaled by 0.125 in the qkv GEMM -> no *0.125f here.
// ---------------------------------------------------------------------------
__global__ __launch_bounds__(256, 4) void attn_part(
    const unsigned short* __restrict__ qkv,
    unsigned short* __restrict__ Opart, float* __restrict__ Lpart)
{
    const int h  = blockIdx.y;
    const int q0 = blockIdx.x * 128;
    const int ks = blockIdx.z;          // keys ks*512 .. +511
    const int tid  = threadIdx.x;
    const int wave = tid >> 6, lane = tid & 63;
    const int l32  = lane & 31, half = lane >> 5;

    __shared__ unsigned short Ks[2][64][72];   // [buf][key][d]
    __shared__ unsigned short Vt[2][64][72];   // [buf][d][key]

    const unsigned short* qp = qkv + (size_t)(q0 + wave * 32 + l32) * 3072 + h * 64 + half * 8;
    s16x8 qb[4];
    #pragma unroll
    for (int c = 0; c < 4; c++)
        qb[c] = *(const s16x8*)(qp + c * 16);

    f32x16 o0 = {}, o1 = {};
    float lsum = 0.f;

    uint4 r0, r1, r2, r3;               // staged regs (K or V path)

    auto issue = [&](int t) {
        const int kt = ks * 512 + t * 64;
        if (tid < 128) {
            int g  = tid & 15;
            int d0 = (tid >> 4) * 8;
            const unsigned short* gv = qkv + (size_t)(kt + 4 * g) * 3072 + 2048 + h * 64 + d0;
            r0 = *(const uint4*)gv;
            r1 = *(const uint4*)(gv + 3072);
            r2 = *(const uint4*)(gv + 6144);
            r3 = *(const uint4*)(gv + 9216);
        } else {
            int u = tid - 128;
            int key = u & 63;
            int dh = (u >> 6) * 32;
            const unsigned short* gk = qkv + (size_t)(kt + key) * 3072 + 1024 + h * 64 + dh;
            const uint4* g4 = (const uint4*)gk;
            r0 = g4[0]; r1 = g4[1]; r2 = g4[2]; r3 = g4[3];
        }
    };
    auto commit = [&](int p) {
        if (tid < 128) {
            int g  = tid & 15;
            int d0 = (tid >> 4) * 8;
            unsigned short a0[8], a1[8], a2[8], a3[8];
            *(uint4*)a0 = r0; *(uint4*)a1 = r1;
            *(uint4*)a2 = r2; *(uint4*)a3 = r3;
            #pragma unroll
            for (int d = 0; d < 8; d++) {
                ushort4 w;
                w.x = a0[d]; w.y = a1[d]; w.z = a2[d]; w.w = a3[d];
                *(ushort4*)&Vt[p][d0 + d][4 * g] = w;
            }
        } else {
            int u = tid - 128;
            int key = u & 63;
            int dh = (u >> 6) * 32;
            *(uint4*)&Ks[p][key][dh]      = r0;
            *(uint4*)&Ks[p][key][dh + 8]  = r1;
            *(uint4*)&Ks[p][key][dh + 16] = r2;
            *(uint4*)&Ks[p][key][dh + 24] = r3;
        }
    };

    issue(0);
    commit(0);
    __syncthreads();

    for (int t = 0; t < 8; t++) {
        const int p = t & 1;
        if (t < 7) issue(t + 1);        // loads in flight under compute

        #pragma unroll
        for (int g = 0; g < 2; g++) {
            f32x16 s = {};
            #pragma unroll
            for (int c = 0; c < 4; c++) {
                s16x8 ka = *(const s16x8*)&Ks[p][g * 32 + l32][c * 16 + half * 8];
                s = mfma32(ka, qb[c], s);
            }
            #pragma unroll
            for (int f = 0; f < 2; f++) {
                float e[8];
                #pragma unroll
                for (int j = 0; j < 8; j++) {
                    e[j] = __expf(s[8 * f + j]);   // scale folded into Q
                    lsum += e[j];
                }
                // RNE-packed pairs (bit-identical P to LDS baseline)
                unsigned w0 = pack2bf(e[0], e[1]);   // lo0
                unsigned w1 = pack2bf(e[2], e[3]);   // lo1
                unsigned w2 = pack2bf(e[4], e[5]);   // hi0
                unsigned w3 = pack2bf(e[6], e[7]);   // hi1
                // DST=lo, SRC=hi: dst'=word0/1, src'=word2/3
                asm("v_permlane32_swap_b32 %0, %1" : "+v"(w0), "+v"(w2));
                asm("v_permlane32_swap_b32 %0, %1" : "+v"(w1), "+v"(w3));
                u32x4 wv; wv.x = w0; wv.y = w1; wv.z = w2; wv.w = w3;
                s16x8 pa = __builtin_bit_cast(s16x8, wv);
                const int c = 2 * g + f;
                s16x8 v0 = *(const s16x8*)&Vt[p][l32][c * 16 + half * 8];
                s16x8 v1 = *(const s16x8*)&Vt[p][32 + l32][c * 16 + half * 8];
                o0 = mfma32(pa, v0, o0);
                o1 = mfma32(pa, v1, o1);
            }
        }

        if (t < 7) commit(p ^ 1);       // write NEXT buffer (disjoint from reads)
        __syncthreads();
    }

    lsum += __shfl_xor(lsum, 32, 64);

    const int mq = q0 + wave * 32;
    unsigned short* opBase = Opart + (size_t)ks * 2048 * 1024;
    #pragma unroll
    for (int r = 0; r < 16; r++) {
        int qr = (r & 3) + 8 * (r >> 2) + 4 * half;
        unsigned short* op = opBase + (size_t)(mq + qr) * 1024 + h * 64;
        op[l32]      = f2bf(o0[r]);
        op[32 + l32] = f2bf(o1[r]);
    }
    if (half == 0)
        Lpart[((size_t)ks * 2048 + mq + l32) * 16 + h] = lsum;
}

// ---------------------------------------------------------------------------
// Combine 4 bf16 split-K partials: ab = (sum n_i) / (sum l_i), bf16.
// ---------------------------------------------------------------------------
__global__ __launch_bounds__(256) void combine(
    const unsigned short* __restrict__ Opart, const float* __restrict__ Lpart,
    unsigned short* __restrict__ ab)
{
    size_t e = ((size_t)blockIdx.x * 256 + threadIdx.x) * 4;
    int tok = (int)(e >> 10);
    int h = (int)((e & 1023) >> 6);
    float l = 0.f;
    #pragma unroll
    for (int s = 0; s < 4; s++)
        l += Lpart[((size_t)s * 2048 + tok) * 16 + h];
    float inv = 1.0f / l;
    float a0 = 0.f, a1 = 0.f, a2 = 0.f, a3 = 0.f;
    #pragma unroll
    for (int s = 0; s < 4; s++) {
        ushort4 n = *(const ushort4*)(Opart + (size_t)s * 2048 * 1024 + e);
        a0 += bf2f(n.x); a1 += bf2f(n.y); a2 += bf2f(n.z); a3 += bf2f(n.w);
    }
    ushort4 w;
    w.x = f2bf(a0 * inv);
    w.y = f2bf(a1 * inv);
    w.z = f2bf(a2 * inv);
    w.w = f2bf(a3 * inv);
    *(ushort4*)(ab + e) = w;
}

extern "C" void kernel_launch(void* const* d_in, const int* in_sizes, int n_in,
                              void* d_out, int out_size, void* d_ws, size_t ws_size,
                              hipStream_t stream)
{
    const float* x  = (const float*)d_in[0];
    const float* wq = (const float*)d_in[1];
    const float* wk = (const float*)d_in[2];
    const float* wv = (const float*)d_in[3];
    const float* wp = (const float*)d_in[4];

    unsigned short* xb    = (unsigned short*)d_ws;        // 2M shorts
    unsigned short* wqkvb = xb    + 2u * 1024 * 1024;     // 3M
    unsigned short* wpb   = wqkvb + 3u * 1024 * 1024;     // 1M
    unsigned short* qkv   = wpb   + 1u * 1024 * 1024;     // 6M
    unsigned short* ab    = qkv   + 2048u * 3072;         // 2M
    unsigned short* Opart = ab    + 2u * 1024 * 1024;     // 4 x 2048 x 1024 bf16
    float* Lpart = (float*)(Opart + 4u * 2048 * 1024);    // 4 x 2048 x 16 fp32

    convert_all<<<6144, 256, 0, stream>>>(x, wq, wk, wv, wp, xb, wqkvb, wpb);
    // qkv GEMM with fused RoPE: 64x128 tile -> grid (24, 32) = 768 blocks
    // (128x128 measured SLOWER at this shape: 384 blocks -> occ 7.3%, 57us)
    gemm_mfma<64, 128, 0, 1><<<dim3(24, 32), 256, 0, stream>>>(
        xb, wqkvb, qkv, 3072);
    attn_part<<<dim3(16, 16, 4), 256, 0, stream>>>(qkv, Opart, Lpart);
    combine<<<2048, 256, 0, stream>>>(Opart, Lpart, ab);
    // proj: 64x64 tile, full K, fp32 out -> grid (16, 32) = 512 blocks
    gemm_mfma<64, 64, 1, 0><<<dim3(16, 32), 256, 0, stream>>>(
        ab, wpb, d_out, 1024);
}

// Round 8
// 150.097 us; speedup vs baseline: 1.6122x; 1.6122x over previous
//
#include <hip/hip_runtime.h>

typedef short s16x8 __attribute__((ext_vector_type(8)));
typedef float f32x4 __attribute__((ext_vector_type(4)));
typedef float f32x16 __attribute__((ext_vector_type(16)));
typedef unsigned int u32x4 __attribute__((ext_vector_type(4)));

__device__ __forceinline__ unsigned short f2bf(float f) {
    unsigned int u = __float_as_uint(f);
    u += 0x7fff + ((u >> 16) & 1);   // RNE
    return (unsigned short)(u >> 16);
}
__device__ __forceinline__ float bf2f(unsigned short h) {
    return __uint_as_float(((unsigned int)h) << 16);
}
__device__ __forceinline__ unsigned pack2bf(float lo, float hi) {
    return (unsigned)f2bf(lo) | ((unsigned)f2bf(hi) << 16);   // RNE both halves
}
__device__ __forceinline__ f32x4 mfma16(s16x8 a, s16x8 b, f32x4 c) {
    return __builtin_amdgcn_mfma_f32_16x16x32_bf16(a, b, c, 0, 0, 0);
}
__device__ __forceinline__ f32x16 mfma32(s16x8 a, s16x8 b, f32x16 c) {
    return __builtin_amdgcn_mfma_f32_32x32x16_bf16(a, b, c, 0, 0, 0);
}
__device__ __forceinline__ void async16(const void* g, void* l) {
    __builtin_amdgcn_global_load_lds(
        (const __attribute__((address_space(1))) void*)g,
        (__attribute__((address_space(3))) void*)l, 16, 0, 0);
}

#define ROPE_C (-13.287712379549449f / 32.0f)

// ---------------------------------------------------------------------------
// fp32 -> bf16: x -> xb, wq|wk|wv -> wqkvb, wp -> wpb.
// ---------------------------------------------------------------------------
__global__ __launch_bounds__(256) void convert_all(
    const float* __restrict__ x,  const float* __restrict__ wq,
    const float* __restrict__ wk, const float* __restrict__ wv,
    const float* __restrict__ wp,
    unsigned short* __restrict__ xb, unsigned short* __restrict__ wqkvb,
    unsigned short* __restrict__ wpb)
{
    const size_t XN = 2048u * 1024u, WN = 1024u * 1024u;
    size_t e = ((size_t)blockIdx.x * 256 + threadIdx.x) * 4;
    const float* s; unsigned short* d;
    if (e < XN)                { s = x  + e;               d = xb    + e; }
    else if (e < XN + WN)      { s = wq + (e - XN);        d = wqkvb + (e - XN); }
    else if (e < XN + 2 * WN)  { s = wk + (e - XN - WN);   d = wqkvb + (e - XN); }
    else if (e < XN + 3 * WN)  { s = wv + (e - XN - 2*WN); d = wqkvb + (e - XN); }
    else                       { s = wp + (e - XN - 3*WN); d = wpb   + (e - XN - 3*WN); }
    float4 v = *(const float4*)s;
    ushort4 o;
    o.x = f2bf(v.x); o.y = f2bf(v.y); o.z = f2bf(v.z); o.w = f2bf(v.w);
    *(ushort4*)d = o;
}

// ---------------------------------------------------------------------------
// bf16 GEMM (m97 structure, BK=64): C = A[M x 1024] * B[N x 1024]^T.
// BM x BN tile, 4 waves (2x2), wave tile (BM/2)x(BN/2), global_load_lds.
// ROPE=1 (requires BN=128): n-blocks < 16 are q/k sections of the fused qkv
// output; wave tile = 64 cols = one head.
//
// *** RoPE binding order IS CORRECT AS WRITTEN — do not "fix" it. ***
// __sincosf(ang,&c,&s) binds c=sin(ang), s=cos(ang); the update
//   q'[i] = e0*c + e1*s ; q'[i+32] = e1*c - e0*s
// is then R(theta - pi/2): the reference rotation composed with a CONSTANT
// 90-degree rotation. Applied identically to q and k, the relative rotation
// R(th_n - th_m) — the only thing logits see — matches the reference
// exactly. Binding sin-first (R4) gives R(-theta) -> INVERSE relative
// rotation -> absmax 2.9e-2 fail.
//
// Q-prescale: q section (n0<1024) additionally scaled by 0.125 = 2^-3
// (exact in bf16 -> exp argument in attn is BIT-IDENTICAL to scaling at
// QK time); removes the *0.125f VALU mul from the attn hot loop.
// Verified passing in R7 (absmax 2.441e-4).
//
// NOTE (R3): at M=2048,N=3072 the 128x128 tile gives only 384 blocks
// (occupancy 7.3%, MfmaUtil 7.9%, 57us) — 64x128 (768 blocks) is right for
// this shape. __sincosf fast path: angle err <= 2048*2^-24 ~ 1.2e-4 rad,
// output perturbation ~1e-4 << 9.7e-4 threshold.
// ---------------------------------------------------------------------------
template<int BM, int BN, int C32, int ROPE>
__global__ __launch_bounds__(256) void gemm_mfma(
    const unsigned short* __restrict__ A,
    const unsigned short* __restrict__ B,
    void* __restrict__ C, int Ntot)
{
    constexpr int MT = BM / 32, NT = BN / 32;
    __shared__ unsigned short As[BM * 64];
    __shared__ unsigned short Bs[BN * 64];

    const int tid  = threadIdx.x;
    const int wave = tid >> 6, lane = tid & 63;
    const int l16  = lane & 15, quad = lane >> 4;
    const int m0   = blockIdx.y * BM, n0 = blockIdx.x * BN;
    const int wm   = (wave & 1) * (BM / 2), wn = (wave >> 1) * (BN / 2);

    const int srow8 = lane >> 3;        // 0..7
    const int scol  = (lane & 7) * 8;   // 0..56

    f32x4 acc[MT][NT] = {};

    for (int k0 = 0; k0 < 1024; k0 += 64) {
        #pragma unroll
        for (int i = 0; i < BM / 32; i++) {
            int j = wave * (BM / 32) + i;
            async16(A + (size_t)(m0 + j * 8 + srow8) * 1024 + k0 + scol, &As[j * 512]);
        }
        #pragma unroll
        for (int i = 0; i < BN / 32; i++) {
            int j = wave * (BN / 32) + i;
            async16(B + (size_t)(n0 + j * 8 + srow8) * 1024 + k0 + scol, &Bs[j * 512]);
        }
        __syncthreads();

        #pragma unroll
        for (int ks = 0; ks < 2; ks++) {
            s16x8 af[MT], bfr[NT];
            #pragma unroll
            for (int mt = 0; mt < MT; mt++)
                af[mt] = *(const s16x8*)&As[(wm + mt * 16 + l16) * 64 + ks * 32 + quad * 8];
            #pragma unroll
            for (int nt = 0; nt < NT; nt++)
                bfr[nt] = *(const s16x8*)&Bs[(wn + nt * 16 + l16) * 64 + ks * 32 + quad * 8];
            #pragma unroll
            for (int mt = 0; mt < MT; mt++)
                #pragma unroll
                for (int nt = 0; nt < NT; nt++)
                    acc[mt][nt] = mfma16(af[mt], bfr[nt], acc[mt][nt]);
        }
        __syncthreads();
    }

    // Fused RoPE on q/k sections (in-register, fp32, before bf16 store)
    if constexpr (ROPE) {
        if (n0 < 2048) {
            const float sc = (n0 < 1024) ? 0.125f : 1.0f;   // Q-prescale
            #pragma unroll
            for (int mt = 0; mt < MT; mt++)
                #pragma unroll
                for (int r = 0; r < 4; r++) {
                    int m = m0 + wm + mt * 16 + quad * 4 + r;   // token
                    #pragma unroll
                    for (int nt = 0; nt < 2; nt++) {
                        int i = nt * 16 + l16;                  // 0..31 in head
                        float ang = (float)m * exp2f((float)i * ROPE_C);
                        float c, s;
                        __sincosf(ang, &c, &s);   // c=sin, s=cos — see header note
                        c *= sc; s *= sc;
                        float e0 = acc[mt][nt][r], e1 = acc[mt][nt + 2][r];
                        acc[mt][nt][r]     = e0 * c + e1 * s;
                        acc[mt][nt + 2][r] = e1 * c - e0 * s;
                    }
                }
        }
    }

    // C/D layout: col = lane&15, row = quad*4 + reg
    #pragma unroll
    for (int mt = 0; mt < MT; mt++)
        #pragma unroll
        for (int nt = 0; nt < NT; nt++)
            #pragma unroll
            for (int r = 0; r < 4; r++) {
                int m = m0 + wm + mt * 16 + quad * 4 + r;
                int n = n0 + wn + nt * 16 + l16;
                size_t idx = (size_t)m * Ntot + n;
                if (C32) ((float*)C)[idx] = acc[mt][nt][r];
                else     ((unsigned short*)C)[idx] = f2bf(acc[mt][nt][r]);
            }
}

// ---------------------------------------------------------------------------
// Split-K flash attention, 32x32x16 MFMA, operand-swapped QK (verified r12).
// 1024 blocks, XCD-swizzled 1D grid (R8):
//   The 16 q-blocks sharing one (head, ksplit) K/V slice are given dispatch
//   ids congruent mod 8 -> same XCD under round-robin -> each XCD's L2 holds
//   only 8 slices (1MB << 4MB). R7 measured 70MB FETCH (6x overfetch, L2
//   thrash across XCDs) with the naive (x=qblk fastest) 3D grid.
//   decode: member=(bid>>3)&15 (q-block), slice=(bid&7)+8*(bid>>7),
//   h=slice&15, ks=slice>>4. Bijective on [0,1024).
// R7 lesson: reg-staged issue-early/commit-late dbuf REGRESSED 3x — compiler
// sank the unforced loads into commit (VGPR stayed 64), nullifying prefetch
// and exposing full load latency at a single barrier. Reverted to the
// R5-proven single-buffer two-barrier body.
//
// P never touches LDS (T12): QK C/D reg r=4c'+j of lane (l32,h) holds
// key 8c'+4h+j, q=l32. PV A-frag word t of fragment c=2g+f needs keys
// 16f+8h+{2t,2t+1}. pack RNE pairs lo0={e0,e1} lo1={e2,e3} hi0={e4,e5}
// hi1={e6,e7}; v_permlane32_swap_b32 dst,src swaps dst[32:63]<->src[0:31]:
//   swap(lo,hi): lo' = word0/1, hi' = word2/3.
// Conversion must stay f2bf RNE (v_cvt_pk truncates -> biased numerator,
// absmax 8e-3, R2 fail). Q is pre-scaled by 0.125 in qkv GEMM.
// ---------------------------------------------------------------------------
__global__ __launch_bounds__(256, 4) void attn_part(
    const unsigned short* __restrict__ qkv,
    unsigned short* __restrict__ Opart, float* __restrict__ Lpart)
{
    const int bid    = blockIdx.x;
    const int member = (bid >> 3) & 15;
    const int slice  = (bid & 7) + 8 * (bid >> 7);
    const int h  = slice & 15;
    const int ks = slice >> 4;
    const int q0 = member * 128;

    const int tid  = threadIdx.x;
    const int wave = tid >> 6, lane = tid & 63;
    const int l32  = lane & 31, half = lane >> 5;

    __shared__ unsigned short Ks[64][72];      // [key][d]
    __shared__ unsigned short Vt[64][72];      // [d][key]

    const unsigned short* qp = qkv + (size_t)(q0 + wave * 32 + l32) * 3072 + h * 64 + half * 8;
    s16x8 qb[4];
    #pragma unroll
    for (int c = 0; c < 4; c++)
        qb[c] = *(const s16x8*)(qp + c * 16);

    f32x16 o0 = {}, o1 = {};
    float lsum = 0.f;

    for (int t = 0; t < 8; t++) {
        const int kt = ks * 512 + t * 64;

        if (tid < 128) {
            int g  = tid & 15;
            int d0 = (tid >> 4) * 8;
            const unsigned short* gv = qkv + (size_t)(kt + 4 * g) * 3072 + 2048 + h * 64 + d0;
            unsigned short a0[8], a1[8], a2[8], a3[8];
            *(uint4*)a0 = *(const uint4*)gv;
            *(uint4*)a1 = *(const uint4*)(gv + 3072);
            *(uint4*)a2 = *(const uint4*)(gv + 6144);
            *(uint4*)a3 = *(const uint4*)(gv + 9216);
            #pragma unroll
            for (int d = 0; d < 8; d++) {
                ushort4 w;
                w.x = a0[d]; w.y = a1[d]; w.z = a2[d]; w.w = a3[d];
                *(ushort4*)&Vt[d0 + d][4 * g] = w;
            }
        } else {
            int u = tid - 128;
            int key = u & 63;
            int dh = (u >> 6) * 32;
            const unsigned short* gk = qkv + (size_t)(kt + key) * 3072 + 1024 + h * 64 + dh;
            const uint4* g4 = (const uint4*)gk;
            uint4 k0 = g4[0], k1 = g4[1], k2 = g4[2], k3 = g4[3];
            *(uint4*)&Ks[key][dh]      = k0;
            *(uint4*)&Ks[key][dh + 8]  = k1;
            *(uint4*)&Ks[key][dh + 16] = k2;
            *(uint4*)&Ks[key][dh + 24] = k3;
        }
        __syncthreads();

        #pragma unroll
        for (int g = 0; g < 2; g++) {
            f32x16 s = {};
            #pragma unroll
            for (int c = 0; c < 4; c++) {
                s16x8 ka = *(const s16x8*)&Ks[g * 32 + l32][c * 16 + half * 8];
                s = mfma32(ka, qb[c], s);
            }
            #pragma unroll
            for (int f = 0; f < 2; f++) {
                float e[8];
                #pragma unroll
                for (int j = 0; j < 8; j++) {
                    e[j] = __expf(s[8 * f + j]);   // scale folded into Q
                    lsum += e[j];
                }
                // RNE-packed pairs (bit-identical P to LDS baseline)
                unsigned w0 = pack2bf(e[0], e[1]);   // lo0
                unsigned w1 = pack2bf(e[2], e[3]);   // lo1
                unsigned w2 = pack2bf(e[4], e[5]);   // hi0
                unsigned w3 = pack2bf(e[6], e[7]);   // hi1
                // DST=lo, SRC=hi: dst'=word0/1, src'=word2/3
                asm("v_permlane32_swap_b32 %0, %1" : "+v"(w0), "+v"(w2));
                asm("v_permlane32_swap_b32 %0, %1" : "+v"(w1), "+v"(w3));
                u32x4 wv; wv.x = w0; wv.y = w1; wv.z = w2; wv.w = w3;
                s16x8 pa = __builtin_bit_cast(s16x8, wv);
                const int c = 2 * g + f;
                s16x8 v0 = *(const s16x8*)&Vt[l32][c * 16 + half * 8];
                s16x8 v1 = *(const s16x8*)&Vt[32 + l32][c * 16 + half * 8];
                o0 = mfma32(pa, v0, o0);
                o1 = mfma32(pa, v1, o1);
            }
        }
        __syncthreads();
    }

    lsum += __shfl_xor(lsum, 32, 64);

    const int mq = q0 + wave * 32;
    unsigned short* opBase = Opart + (size_t)ks * 2048 * 1024;
    #pragma unroll
    for (int r = 0; r < 16; r++) {
        int qr = (r & 3) + 8 * (r >> 2) + 4 * half;
        unsigned short* op = opBase + (size_t)(mq + qr) * 1024 + h * 64;
        op[l32]      = f2bf(o0[r]);
        op[32 + l32] = f2bf(o1[r]);
    }
    if (half == 0)
        Lpart[((size_t)ks * 2048 + mq + l32) * 16 + h] = lsum;
}

// ---------------------------------------------------------------------------
// Combine 4 bf16 split-K partials: ab = (sum n_i) / (sum l_i), bf16.
// ---------------------------------------------------------------------------
__global__ __launch_bounds__(256) void combine(
    const unsigned short* __restrict__ Opart, const float* __restrict__ Lpart,
    unsigned short* __restrict__ ab)
{
    size_t e = ((size_t)blockIdx.x * 256 + threadIdx.x) * 4;
    int tok = (int)(e >> 10);
    int h = (int)((e & 1023) >> 6);
    float l = 0.f;
    #pragma unroll
    for (int s = 0; s < 4; s++)
        l += Lpart[((size_t)s * 2048 + tok) * 16 + h];
    float inv = 1.0f / l;
    float a0 = 0.f, a1 = 0.f, a2 = 0.f, a3 = 0.f;
    #pragma unroll
    for (int s = 0; s < 4; s++) {
        ushort4 n = *(const ushort4*)(Opart + (size_t)s * 2048 * 1024 + e);
        a0 += bf2f(n.x); a1 += bf2f(n.y); a2 += bf2f(n.z); a3 += bf2f(n.w);
    }
    ushort4 w;
    w.x = f2bf(a0 * inv);
    w.y = f2bf(a1 * inv);
    w.z = f2bf(a2 * inv);
    w.w = f2bf(a3 * inv);
    *(ushort4*)(ab + e) = w;
}

extern "C" void kernel_launch(void* const* d_in, const int* in_sizes, int n_in,
                              void* d_out, int out_size, void* d_ws, size_t ws_size,
                              hipStream_t stream)
{
    const float* x  = (const float*)d_in[0];
    const float* wq = (const float*)d_in[1];
    const float* wk = (const float*)d_in[2];
    const float* wv = (const float*)d_in[3];
    const float* wp = (const float*)d_in[4];

    unsigned short* xb    = (unsigned short*)d_ws;        // 2M shorts
    unsigned short* wqkvb = xb    + 2u * 1024 * 1024;     // 3M
    unsigned short* wpb   = wqkvb + 3u * 1024 * 1024;     // 1M
    unsigned short* qkv   = wpb   + 1u * 1024 * 1024;     // 6M
    unsigned short* ab    = qkv   + 2048u * 3072;         // 2M
    unsigned short* Opart = ab    + 2u * 1024 * 1024;     // 4 x 2048 x 1024 bf16
    float* Lpart = (float*)(Opart + 4u * 2048 * 1024);    // 4 x 2048 x 16 fp32

    convert_all<<<6144, 256, 0, stream>>>(x, wq, wk, wv, wp, xb, wqkvb, wpb);
    // qkv GEMM with fused RoPE: 64x128 tile -> grid (24, 32) = 768 blocks
    // (128x128 measured SLOWER at this shape: 384 blocks -> occ 7.3%, 57us)
    gemm_mfma<64, 128, 0, 1><<<dim3(24, 32), 256, 0, stream>>>(
        xb, wqkvb, qkv, 3072);
    // attn: 1D XCD-swizzled grid (see kernel header)
    attn_part<<<dim3(1024), 256, 0, stream>>>(qkv, Opart, Lpart);
    combine<<<2048, 256, 0, stream>>>(Opart, Lpart, ab);
    // proj: 64x64 tile, full K, fp32 out -> grid (16, 32) = 512 blocks
    gemm_mfma<64, 64, 1, 0><<<dim3(16, 32), 256, 0, stream>>>(
        ab, wpb, d_out, 1024);
}